// Round 1
// baseline (100.853 us; speedup 1.0000x reference)
//
#include <hip/hip_runtime.h>
#include <math.h>

// C = A * B for row-major 3x3 doubles
__device__ __forceinline__ void mm3(const double* __restrict__ A,
                                    const double* __restrict__ Bm,
                                    double* __restrict__ C) {
#pragma unroll
    for (int i = 0; i < 3; ++i) {
#pragma unroll
        for (int j = 0; j < 3; ++j) {
            C[i*3+j] = fma(A[i*3+0], Bm[0*3+j],
                       fma(A[i*3+1], Bm[1*3+j],
                           A[i*3+2] * Bm[2*3+j]));
        }
    }
}

__global__ __launch_bounds__(256) void lie_expm_kernel(const float* __restrict__ v,
                                                       float* __restrict__ out,
                                                       int n) {
    int tid = blockIdx.x * blockDim.x + threadIdx.x;
    if (tid >= n) return;

    // (B,8) row-major, 32B per row, base 16B-aligned -> two float4 loads
    const float4* vv = reinterpret_cast<const float4*>(v);
    float4 p0 = vv[2*(size_t)tid + 0];
    float4 p1 = vv[2*(size_t)tid + 1];
    double x0 = p0.x, x1 = p0.y, x2 = p0.z, x3 = p0.w;
    double x4 = p1.x, x5 = p1.y, x6 = p1.z, x7 = p1.w;

    // A = sum_k v_k * G_k  (sl(3) basis from the reference)
    double A[9];
    A[0] = x3 + x4;  A[1] = x5 - x2;  A[2] = x0;
    A[3] = x2 + x5;  A[4] = x3 - x4;  A[5] = x1;
    A[6] = x6;       A[7] = x7;       A[8] = -2.0 * x3;

    // 1-norm (max abs column sum) upper-bounds the spectral radius
    double c0 = fabs(A[0]) + fabs(A[3]) + fabs(A[6]);
    double c1 = fabs(A[1]) + fabs(A[4]) + fabs(A[7]);
    double c2 = fabs(A[2]) + fabs(A[5]) + fabs(A[8]);
    double nrm = fmax(c0, fmax(c1, c2));

    // scaling: ||A/2^s|| <= 0.25  (s <= ~8 for N(0,1) inputs)
    int s = 0;
    while (nrm > 0.25) { nrm *= 0.5; ++s; }
    double sc = ldexp(1.0, -s);
#pragma unroll
    for (int i = 0; i < 9; ++i) A[i] *= sc;

    // Taylor series exp(A) = I + A + A^2/2! + ... + A^14/14!
    // truncation error at ||A||<=0.25: 0.25^15/15! ~ 7e-22
    double E[9], P[9], T[9];
#pragma unroll
    for (int i = 0; i < 9; ++i) { E[i] = A[i]; P[i] = A[i]; }
    E[0] += 1.0; E[4] += 1.0; E[8] += 1.0;

    const double rn[13] = {1.0/2, 1.0/3, 1.0/4, 1.0/5, 1.0/6, 1.0/7, 1.0/8,
                           1.0/9, 1.0/10, 1.0/11, 1.0/12, 1.0/13, 1.0/14};
#pragma unroll
    for (int k = 0; k < 13; ++k) {
        mm3(P, A, T);
#pragma unroll
        for (int i = 0; i < 9; ++i) { P[i] = T[i] * rn[k]; E[i] += P[i]; }
    }

    // undo scaling: E <- E^(2^s)
    for (int i = 0; i < s; ++i) {
        mm3(E, E, T);
#pragma unroll
        for (int j = 0; j < 9; ++j) E[j] = T[j];
    }

    // homogeneous normalization by H[2][2], cast to fp32
    double inv = 1.0 / E[8];
    float* o = out + (size_t)tid * 9;
#pragma unroll
    for (int i = 0; i < 9; ++i) o[i] = (float)(E[i] * inv);
}

extern "C" void kernel_launch(void* const* d_in, const int* in_sizes, int n_in,
                              void* d_out, int out_size, void* d_ws, size_t ws_size,
                              hipStream_t stream) {
    const float* v = (const float*)d_in[0];
    float* out = (float*)d_out;
    int n = in_sizes[0] / 8;   // B rows of 8 coefficients
    int block = 256;
    int grid = (n + block - 1) / block;
    lie_expm_kernel<<<grid, block, 0, stream>>>(v, out, n);
}

// Round 2
// 89.416 us; speedup vs baseline: 1.1279x; 1.1279x over previous
//
#include <hip/hip_runtime.h>
#include <math.h>

// C = A * B for row-major 3x3 doubles
__device__ __forceinline__ void mm3(const double* __restrict__ A,
                                    const double* __restrict__ Bm,
                                    double* __restrict__ C) {
#pragma unroll
    for (int i = 0; i < 3; ++i) {
#pragma unroll
        for (int j = 0; j < 3; ++j) {
            C[i*3+j] = fma(A[i*3+0], Bm[0*3+j],
                       fma(A[i*3+1], Bm[1*3+j],
                           A[i*3+2] * Bm[2*3+j]));
        }
    }
}

#define BLOCK 256

__global__ __launch_bounds__(BLOCK) void lie_expm_kernel(const float* __restrict__ v,
                                                         float* __restrict__ out,
                                                         int n) {
    __shared__ float lds[BLOCK * 9];

    int tid = threadIdx.x;
    int gid = blockIdx.x * BLOCK + tid;
    bool active = gid < n;

    float oloc[9];

    if (active) {
        const float4* vv = reinterpret_cast<const float4*>(v);
        float4 p0 = vv[2*(size_t)gid + 0];
        float4 p1 = vv[2*(size_t)gid + 1];
        double x0 = p0.x, x1 = p0.y, x2 = p0.z, x3 = p0.w;
        double x4 = p1.x, x5 = p1.y, x6 = p1.z, x7 = p1.w;

        // A = sum_k v_k * G_k  (sl(3) basis)
        double A[9];
        A[0] = x3 + x4;  A[1] = x5 - x2;  A[2] = x0;
        A[3] = x2 + x5;  A[4] = x3 - x4;  A[5] = x1;
        A[6] = x6;       A[7] = x7;       A[8] = -2.0 * x3;

        // 1-norm (max abs column sum)
        double c0 = fabs(A[0]) + fabs(A[3]) + fabs(A[6]);
        double c1 = fabs(A[1]) + fabs(A[4]) + fabs(A[7]);
        double c2 = fabs(A[2]) + fabs(A[5]) + fabs(A[8]);
        double nrm = fmax(c0, fmax(c1, c2));

        // Pade-13 theta (Higham 2005)
        const double theta13 = 5.371920351148152;
        double r = nrm * (1.0 / theta13);
        int s = 0;
        if (r > 1.0) {
            // s = floor(log2 r) + 1 >= ceil(log2 r)  (branch-free exponent grab)
            int hi = __double2hiint(r);
            s = ((hi >> 20) & 0x7ff) - 1023 + 1;
        }
        double sc = __hiloint2double((1023 - s) << 20, 0);  // 2^-s
#pragma unroll
        for (int i = 0; i < 9; ++i) A[i] *= sc;

        // Pade-13 coefficients
        const double b0  = 64764752532480000.0, b1  = 32382376266240000.0;
        const double b2  = 7771770303897600.0,  b3  = 1187353796428800.0;
        const double b4  = 129060195264000.0,   b5  = 10559470521600.0;
        const double b6  = 670442572800.0,      b7  = 33522128640.0;
        const double b8  = 1323241920.0,        b9  = 40840800.0;
        const double b10 = 960960.0,            b11 = 16380.0;
        const double b12 = 182.0,               b13 = 1.0;

        double A2[9], A4[9], A6[9];
        mm3(A, A, A2);
        mm3(A2, A2, A4);
        mm3(A4, A2, A6);

        // V = A6*(b12*A6 + b10*A4 + b8*A2) + b6*A6 + b4*A4 + b2*A2 + b0*I
        double W[9], V[9];
#pragma unroll
        for (int i = 0; i < 9; ++i)
            W[i] = fma(b12, A6[i], fma(b10, A4[i], b8 * A2[i]));
        mm3(A6, W, V);
#pragma unroll
        for (int i = 0; i < 9; ++i)
            V[i] += fma(b6, A6[i], fma(b4, A4[i], b2 * A2[i]));
        V[0] += b0; V[4] += b0; V[8] += b0;

        // U = A*(A6*(b13*A6 + b11*A4 + b9*A2) + b7*A6 + b5*A4 + b3*A2 + b1*I)
        double Z[9], U[9];
#pragma unroll
        for (int i = 0; i < 9; ++i)
            W[i] = fma(b13, A6[i], fma(b11, A4[i], b9 * A2[i]));
        mm3(A6, W, Z);
#pragma unroll
        for (int i = 0; i < 9; ++i)
            Z[i] += fma(b7, A6[i], fma(b5, A4[i], b3 * A2[i]));
        Z[0] += b1; Z[4] += b1; Z[8] += b1;
        mm3(A, Z, U);

        // Solve (V - U) E = (V + U) via 3x3 adjugate
        double M[9], R[9];
#pragma unroll
        for (int i = 0; i < 9; ++i) { M[i] = V[i] - U[i]; R[i] = V[i] + U[i]; }

        double inv[9];
        inv[0] = fma(M[4], M[8], -M[5]*M[7]);
        inv[1] = fma(M[2], M[7], -M[1]*M[8]);
        inv[2] = fma(M[1], M[5], -M[2]*M[4]);
        inv[3] = fma(M[5], M[6], -M[3]*M[8]);
        inv[4] = fma(M[0], M[8], -M[2]*M[6]);
        inv[5] = fma(M[2], M[3], -M[0]*M[5]);
        inv[6] = fma(M[3], M[7], -M[4]*M[6]);
        inv[7] = fma(M[1], M[6], -M[0]*M[7]);
        inv[8] = fma(M[0], M[4], -M[1]*M[3]);
        double det = fma(M[0], inv[0], fma(M[1], inv[3], M[2]*inv[6]));
        double rd = 1.0 / det;
#pragma unroll
        for (int i = 0; i < 9; ++i) inv[i] *= rd;

        double E[9], T[9];
        mm3(inv, R, E);

        // undo scaling: E <- E^(2^s)   (s == 0 for the vast majority of lanes)
        for (int i = 0; i < s; ++i) {
            mm3(E, E, T);
#pragma unroll
            for (int j = 0; j < 9; ++j) E[j] = T[j];
        }

        // homogeneous normalization
        double invh = 1.0 / E[8];
#pragma unroll
        for (int i = 0; i < 9; ++i) oloc[i] = (float)(E[i] * invh);
    }

    // coalesced store via LDS: block covers BLOCK*9 contiguous floats
    if (active) {
#pragma unroll
        for (int j = 0; j < 9; ++j) lds[tid * 9 + j] = oloc[j];
    }
    __syncthreads();

    size_t base = (size_t)blockIdx.x * (BLOCK * 9);
    int count = n - blockIdx.x * BLOCK;           // valid elements in this block
    if (count > BLOCK) count = BLOCK;
    int total = count * 9;
#pragma unroll
    for (int i = 0; i < 9; ++i) {
        int idx = i * BLOCK + tid;
        if (idx < total) out[base + idx] = lds[idx];
    }
}

extern "C" void kernel_launch(void* const* d_in, const int* in_sizes, int n_in,
                              void* d_out, int out_size, void* d_ws, size_t ws_size,
                              hipStream_t stream) {
    const float* v = (const float*)d_in[0];
    float* out = (float*)d_out;
    int n = in_sizes[0] / 8;   // B rows of 8 coefficients
    int grid = (n + BLOCK - 1) / BLOCK;
    lie_expm_kernel<<<grid, BLOCK, 0, stream>>>(v, out, n);
}